// Round 1
// baseline (185.160 us; speedup 1.0000x reference)
//
#include <hip/hip_runtime.h>
#include <math.h>

#define BATCH 8
#define NTOK  4096
#define DIM   64
#define BM    128
#define NT    (NTOK / BM)            // 32 tiles per dim
#define TPB   (NT * (NT + 1) / 2)    // 528 upper-tri tile pairs per batch
#define GRID  (BATCH * TPB)          // 4224 blocks
#define KAPPA 0.5f
#define LOG2E 1.4426950408889634f
#define LN2   0.6931471805599453f

typedef _Float16 f16x8 __attribute__((ext_vector_type(8)));
typedef float    f32x16 __attribute__((ext_vector_type(16)));

// exp2: v_exp_f32 IS base-2, so the log2-domain epilogue saves one v_mul per
// element vs __expf (which emits v_mul(log2e) + v_exp).
__device__ __forceinline__ float EXP2(float x) {
#if __has_builtin(__builtin_amdgcn_exp2f)
    return __builtin_amdgcn_exp2f(x);
#else
    return __expf(x * LN2);
#endif
}

// One block per (batch, upper-tri 128x128 tile pair). Gram tile via
// mfma_f32_32x32x16_f16, per-wave (max, sum-exp2) in log2 domain (no block-
// global max -> one fewer barrier), whole-tile weighting (diag=1, offdiag=2).
// Last block to finish (device-scope atomic counter) merges all (M,S) pairs
// and writes the final scalar -> single kernel node, no second launch.
__global__ __launch_bounds__(256, 3)
void gram_lse_fused(const float* __restrict__ emb, float* __restrict__ ws,
                    unsigned* __restrict__ counter, float* __restrict__ out) {
    // Panels as 16-B units: unit (g, row) at [g*128 + (row^g)], g=k/8 in 0..7.
    // XOR swizzle keeps both staging writes and fragment reads conflict-free.
    __shared__ f16x8 As[8 * BM];   // 16 KB
    __shared__ f16x8 Bs[8 * BM];   // 16 KB
    __shared__ float red_m[4], red_s[4];
    __shared__ float lse8[BATCH];
    __shared__ int   isLast;

    const int tid = threadIdx.x;
    const int bb  = blockIdx.x;
    const int b   = bb / TPB;
    int t = bb - b * TPB;
    int ti = 0;
    while (t >= NT - ti) { t -= NT - ti; ++ti; }
    const int tj = ti + t;

    const float* embA = emb + ((size_t)b * NTOK + (size_t)ti * BM) * DIM;
    const float* embB = emb + ((size_t)b * NTOK + (size_t)tj * BM) * DIM;

    // ---- global fp32 -> LDS f16 staging ----
    {
        const int g  = tid & 7;     // k-group: k = 8g..8g+7
        const int r0 = tid >> 3;    // 0..31
#pragma unroll
        for (int p = 0; p < 4; ++p) {
            const int row = r0 + 32 * p;
            const float4 a0 = *(const float4*)(embA + (size_t)row * DIM + g * 8);
            const float4 a1 = *(const float4*)(embA + (size_t)row * DIM + g * 8 + 4);
            const float4 b0 = *(const float4*)(embB + (size_t)row * DIM + g * 8);
            const float4 b1 = *(const float4*)(embB + (size_t)row * DIM + g * 8 + 4);
            f16x8 pa, pb;
            pa[0] = (_Float16)a0.x; pa[1] = (_Float16)a0.y;
            pa[2] = (_Float16)a0.z; pa[3] = (_Float16)a0.w;
            pa[4] = (_Float16)a1.x; pa[5] = (_Float16)a1.y;
            pa[6] = (_Float16)a1.z; pa[7] = (_Float16)a1.w;
            pb[0] = (_Float16)b0.x; pb[1] = (_Float16)b0.y;
            pb[2] = (_Float16)b0.z; pb[3] = (_Float16)b0.w;
            pb[4] = (_Float16)b1.x; pb[5] = (_Float16)b1.y;
            pb[6] = (_Float16)b1.z; pb[7] = (_Float16)b1.w;
            As[g * BM + (row ^ g)] = pa;
            Bs[g * BM + (row ^ g)] = pb;
        }
    }
    __syncthreads();

    // ---- MFMA: each wave computes a 64x64 subtile (2x2 of 32x32, K=64) ----
    const int lane = tid & 63;
    const int w    = tid >> 6;
    const int half = lane >> 5;    // k-half within fragment
    const int ln31 = lane & 31;
    const int waveR = (w & 1) * 64;
    const int waveC = (w >> 1) * 64;

    f32x16 acc00 = {}, acc01 = {}, acc10 = {}, acc11 = {};
#pragma unroll
    for (int s = 0; s < 4; ++s) {
        const int g = 2 * s + half;
        const f16x8 a0 = As[g * BM + ((waveR + ln31) ^ g)];
        const f16x8 a1 = As[g * BM + ((waveR + 32 + ln31) ^ g)];
        const f16x8 b0 = Bs[g * BM + ((waveC + ln31) ^ g)];
        const f16x8 b1 = Bs[g * BM + ((waveC + 32 + ln31) ^ g)];
        acc00 = __builtin_amdgcn_mfma_f32_32x32x16_f16(a0, b0, acc00, 0, 0, 0);
        acc01 = __builtin_amdgcn_mfma_f32_32x32x16_f16(a0, b1, acc01, 0, 0, 0);
        acc10 = __builtin_amdgcn_mfma_f32_32x32x16_f16(a1, b0, acc10, 0, 0, 0);
        acc11 = __builtin_amdgcn_mfma_f32_32x32x16_f16(a1, b1, acc11, 0, 0, 0);
    }

    // ---- epilogue: per-wave (max, sum-exp2) in log2 domain ----
    const float c2 = KAPPA * LOG2E;
    float lm = acc00[0];
#pragma unroll
    for (int e = 0; e < 16; ++e) {
        lm = fmaxf(lm, acc00[e]); lm = fmaxf(lm, acc01[e]);
        lm = fmaxf(lm, acc10[e]); lm = fmaxf(lm, acc11[e]);
    }
#pragma unroll
    for (int off = 32; off > 0; off >>= 1)
        lm = fmaxf(lm, __shfl_xor(lm, off));
    const float m2 = c2 * lm;       // wave-local max, log2 domain

    float lsum = 0.f;
#pragma unroll
    for (int e = 0; e < 16; ++e) {
        lsum += EXP2(fmaf(c2, acc00[e], -m2));
        lsum += EXP2(fmaf(c2, acc01[e], -m2));
        lsum += EXP2(fmaf(c2, acc10[e], -m2));
        lsum += EXP2(fmaf(c2, acc11[e], -m2));
    }
#pragma unroll
    for (int off = 32; off > 0; off >>= 1)
        lsum += __shfl_xor(lsum, off);
    if (lane == 0) { red_m[w] = m2; red_s[w] = lsum; }
    __syncthreads();

    if (tid == 0) {
        const float M2 = fmaxf(fmaxf(red_m[0], red_m[1]),
                               fmaxf(red_m[2], red_m[3]));
        float S = red_s[0] * EXP2(red_m[0] - M2)
                + red_s[1] * EXP2(red_m[1] - M2)
                + red_s[2] * EXP2(red_m[2] - M2)
                + red_s[3] * EXP2(red_m[3] - M2);
        const float wgt = (ti == tj) ? 1.f : 2.f;
        ws[2 * (size_t)bb]     = M2;
        ws[2 * (size_t)bb + 1] = wgt * S;
        __threadfence();                               // release (M,S) stores
        isLast = (atomicAdd(counter, 1u) == GRID - 1) ? 1 : 0;
    }
    __syncthreads();
    if (!isLast) return;

    // ---- last block: merge all BATCH*TPB (M,S) pairs, write the scalar ----
    __threadfence();                                   // acquire before reads
    for (int bq = w; bq < BATCH; bq += 4) {            // 4 waves, 2 batches each
        const float* p = ws + (size_t)bq * TPB * 2;
        float L = -INFINITY;
        for (int idx = lane; idx < TPB; idx += 64) L = fmaxf(L, p[2 * idx]);
#pragma unroll
        for (int off = 32; off > 0; off >>= 1)
            L = fmaxf(L, __shfl_xor(L, off));
        float s = 0.f;
        for (int idx = lane; idx < TPB; idx += 64)
            s += p[2 * idx + 1] * EXP2(p[2 * idx] - L);
#pragma unroll
        for (int off = 32; off > 0; off >>= 1)
            s += __shfl_xor(s, off);
        if (lane == 0) lse8[bq] = LN2 * (L + log2f(s));
    }
    __syncthreads();
    if (tid == 0) {
        float a = 0.f;
        for (int i = 0; i < BATCH; ++i) a += lse8[i];
        out[0] = a * (1.f / BATCH);
    }
}

extern "C" void kernel_launch(void* const* d_in, const int* in_sizes, int n_in,
                              void* d_out, int out_size, void* d_ws, size_t ws_size,
                              hipStream_t stream) {
    const float* emb = (const float*)d_in[0];
    float* out = (float*)d_out;
    float* ws  = (float*)d_ws;   // 2*GRID floats = 33,792 B for (M,S) pairs
    unsigned* counter = (unsigned*)((char*)d_ws + 2 * (size_t)GRID * sizeof(float));

    // ws is re-poisoned by the harness between iterations -> counter must be
    // zeroed every launch. Memset node is graph-capturable.
    hipMemsetAsync(counter, 0, sizeof(unsigned), stream);
    gram_lse_fused<<<GRID, 256, 0, stream>>>(emb, ws, counter, out);
}

// Round 2
// 80.485 us; speedup vs baseline: 2.3005x; 2.3005x over previous
//
#include <hip/hip_runtime.h>
#include <math.h>

#define BATCH 8
#define NTOK  4096
#define DIM   64
#define BM    128
#define NT    (NTOK / BM)            // 32 tiles per dim
#define TPB   (NT * (NT + 1) / 2)    // 528 upper-tri tile pairs per batch
#define KAPPA 0.5f
#define LOG2E 1.4426950408889634f
#define LN2   0.6931471805599453f

typedef _Float16 f16x8 __attribute__((ext_vector_type(8)));
typedef float    f32x16 __attribute__((ext_vector_type(16)));

// v_exp_f32 is natively base-2; log2-domain epilogue saves a v_mul per element.
__device__ __forceinline__ float EXP2(float x) {
#if __has_builtin(__builtin_amdgcn_exp2f)
    return __builtin_amdgcn_exp2f(x);
#else
    return __expf(x * LN2);
#endif
}

// One block per (batch, upper-tri 128x128 tile pair). Gram tile via
// mfma_f32_32x32x16_f16. Epilogue is fully per-wave: each wave reduces its own
// 64x64 subtile to (m2, s) in the log2 domain and lane 0 stores the pair
// directly to ws — no post-MFMA __syncthreads, no cross-wave dependency, no
// serial tid-0 tail (R1 post-mortem: a fence+atomic tail cost ~20 µs/block).
// Whole-tile weighting (diag=1, offdiag=2) keeps it permutation-invariant.
__global__ __launch_bounds__(256, 3)
void gram_lse_partial(const float* __restrict__ emb, float* __restrict__ ws) {
    // Panels as 16-B units: unit (g, row) at [g*128 + (row^g)], g=k/8 in 0..7.
    // XOR swizzle keeps both staging writes and fragment reads conflict-free.
    __shared__ f16x8 As[8 * BM];   // 16 KB
    __shared__ f16x8 Bs[8 * BM];   // 16 KB

    const int tid = threadIdx.x;
    const int bb  = blockIdx.x;
    const int b   = bb / TPB;
    int t = bb - b * TPB;
    int ti = 0;
    while (t >= NT - ti) { t -= NT - ti; ++ti; }
    const int tj = ti + t;

    const float* embA = emb + ((size_t)b * NTOK + (size_t)ti * BM) * DIM;
    const float* embB = emb + ((size_t)b * NTOK + (size_t)tj * BM) * DIM;

    // ---- global fp32 -> LDS f16 staging ----
    {
        const int g  = tid & 7;     // k-group: k = 8g..8g+7
        const int r0 = tid >> 3;    // 0..31
#pragma unroll
        for (int p = 0; p < 4; ++p) {
            const int row = r0 + 32 * p;
            const float4 a0 = *(const float4*)(embA + (size_t)row * DIM + g * 8);
            const float4 a1 = *(const float4*)(embA + (size_t)row * DIM + g * 8 + 4);
            const float4 b0 = *(const float4*)(embB + (size_t)row * DIM + g * 8);
            const float4 b1 = *(const float4*)(embB + (size_t)row * DIM + g * 8 + 4);
            f16x8 pa, pb;
            pa[0] = (_Float16)a0.x; pa[1] = (_Float16)a0.y;
            pa[2] = (_Float16)a0.z; pa[3] = (_Float16)a0.w;
            pa[4] = (_Float16)a1.x; pa[5] = (_Float16)a1.y;
            pa[6] = (_Float16)a1.z; pa[7] = (_Float16)a1.w;
            pb[0] = (_Float16)b0.x; pb[1] = (_Float16)b0.y;
            pb[2] = (_Float16)b0.z; pb[3] = (_Float16)b0.w;
            pb[4] = (_Float16)b1.x; pb[5] = (_Float16)b1.y;
            pb[6] = (_Float16)b1.z; pb[7] = (_Float16)b1.w;
            As[g * BM + (row ^ g)] = pa;
            Bs[g * BM + (row ^ g)] = pb;
        }
    }
    __syncthreads();

    // ---- MFMA: each wave computes a 64x64 subtile (2x2 of 32x32, K=64) ----
    const int lane = tid & 63;
    const int w    = tid >> 6;
    const int half = lane >> 5;    // k-half within fragment
    const int ln31 = lane & 31;
    const int waveR = (w & 1) * 64;
    const int waveC = (w >> 1) * 64;

    f32x16 acc00 = {}, acc01 = {}, acc10 = {}, acc11 = {};
#pragma unroll
    for (int s = 0; s < 4; ++s) {
        const int g = 2 * s + half;
        const f16x8 a0 = As[g * BM + ((waveR + ln31) ^ g)];
        const f16x8 a1 = As[g * BM + ((waveR + 32 + ln31) ^ g)];
        const f16x8 b0 = Bs[g * BM + ((waveC + ln31) ^ g)];
        const f16x8 b1 = Bs[g * BM + ((waveC + 32 + ln31) ^ g)];
        acc00 = __builtin_amdgcn_mfma_f32_32x32x16_f16(a0, b0, acc00, 0, 0, 0);
        acc01 = __builtin_amdgcn_mfma_f32_32x32x16_f16(a0, b1, acc01, 0, 0, 0);
        acc10 = __builtin_amdgcn_mfma_f32_32x32x16_f16(a1, b0, acc10, 0, 0, 0);
        acc11 = __builtin_amdgcn_mfma_f32_32x32x16_f16(a1, b1, acc11, 0, 0, 0);
    }

    // ---- epilogue: per-wave (max, sum-exp2), log2 domain, no barriers ----
    const float c2 = KAPPA * LOG2E;
    float lm = acc00[0];
#pragma unroll
    for (int e = 0; e < 16; ++e) {
        lm = fmaxf(lm, acc00[e]); lm = fmaxf(lm, acc01[e]);
        lm = fmaxf(lm, acc10[e]); lm = fmaxf(lm, acc11[e]);
    }
#pragma unroll
    for (int off = 32; off > 0; off >>= 1)
        lm = fmaxf(lm, __shfl_xor(lm, off));
    const float m2 = c2 * lm;       // wave-local max, log2 domain

    float lsum = 0.f;
#pragma unroll
    for (int e = 0; e < 16; ++e) {
        lsum += EXP2(fmaf(c2, acc00[e], -m2));
        lsum += EXP2(fmaf(c2, acc01[e], -m2));
        lsum += EXP2(fmaf(c2, acc10[e], -m2));
        lsum += EXP2(fmaf(c2, acc11[e], -m2));
    }
#pragma unroll
    for (int off = 32; off > 0; off >>= 1)
        lsum += __shfl_xor(lsum, off);

    if (lane == 0) {
        const float wgt = (ti == tj) ? 1.f : 2.f;
        float2 pr; pr.x = m2; pr.y = wgt * lsum;
        *(float2*)(ws + ((size_t)bb * 4 + w) * 2) = pr;
    }
}

// 1 block, 8 waves: wave w merges batch w's TPB*4 = 2112 (m,s) pairs.
// 2112 = 33*64 exactly -> fully unrolled, statically-indexed (stays in regs).
__global__ __launch_bounds__(512)
void reduce_lse(const float* __restrict__ ws, float* __restrict__ out) {
    const int tid  = threadIdx.x;
    const int w    = tid >> 6;
    const int lane = tid & 63;
    __shared__ float lse8[BATCH];

    const float* p = ws + (size_t)w * TPB * 8;   // batch w: 2112 float2 pairs
    float mv[33], lv[33];
#pragma unroll
    for (int c = 0; c < 33; ++c) {
        const float2 v = *(const float2*)(p + 2 * (lane + 64 * c));
        mv[c] = v.x; lv[c] = v.y;
    }
    float L = mv[0];
#pragma unroll
    for (int c = 1; c < 33; ++c) L = fmaxf(L, mv[c]);
#pragma unroll
    for (int off = 32; off > 0; off >>= 1) L = fmaxf(L, __shfl_xor(L, off));

    float s = 0.f;
#pragma unroll
    for (int c = 0; c < 33; ++c) s += lv[c] * EXP2(mv[c] - L);
#pragma unroll
    for (int off = 32; off > 0; off >>= 1) s += __shfl_xor(s, off);

    if (lane == 0) lse8[w] = LN2 * (L + log2f(s));   // back to natural log
    __syncthreads();
    if (tid == 0) {
        float a = 0.f;
        for (int i = 0; i < BATCH; ++i) a += lse8[i];
        out[0] = a * (1.f / BATCH);
    }
}

extern "C" void kernel_launch(void* const* d_in, const int* in_sizes, int n_in,
                              void* d_out, int out_size, void* d_ws, size_t ws_size,
                              hipStream_t stream) {
    const float* emb = (const float*)d_in[0];
    float* out = (float*)d_out;
    float* ws  = (float*)d_ws;   // BATCH*TPB*4 pairs = 135,168 B

    gram_lse_partial<<<BATCH * TPB, 256, 0, stream>>>(emb, ws);
    reduce_lse<<<1, 512, 0, stream>>>(ws, out);
}